// Round 2
// baseline (900.791 us; speedup 1.0000x reference)
//
#include <hip/hip_runtime.h>
#include <cstddef>

#define SEQ   2048
#define DIM   64
#define NHEAD 32            // B*H = 4*8
#define BM    128           // rows per block (K2)
#define BN    128           // cols per tile  (K2)
#define NT    (SEQ / BN)    // 16 tiles
#define LDT   140           // swizzled stride (floats) for 128-wide LDS tiles
#define WLD   68            // padded stride for 64-wide LDS tiles

// group-shift swizzle: insert 4-float pad every 32 floats.
// Spreads the 16 lanes' 8-float column groups across all bank quads (2-way max).
__device__ __forceinline__ int swz(int c) { return c + ((c >> 5) << 2); }

// ---------------------------------------------------------------------------
// K1: kfT[head][f][s] = relu( sum_d k[head][s][d] * W[f][d] )   (transposed!)
// 64 rows per block; 32 heads * 32 blocks = 1024 blocks.
// ---------------------------------------------------------------------------
__global__ __launch_bounds__(256) void kf_kernel(const float* __restrict__ kin,
                                                 const float* __restrict__ W,
                                                 float* __restrict__ kfT)
{
    __shared__ float Xs[64 * WLD];   // k rows  [r][d]
    __shared__ float Ws[64 * WLD];   // weights [f][d]
    __shared__ float Os[64 * WLD];   // kf^T    [f][r]

    const int tid  = threadIdx.x;
    const int head = blockIdx.x >> 5;
    const int r0   = (blockIdx.x & 31) * 64;

    {   // stage k tile + W (coalesced float4)
        const int rr = tid >> 2;
        const int cc = (tid & 3) * 16;
        const float* gx = kin + ((size_t)head * SEQ + r0 + rr) * DIM + cc;
        const float* gw = W + rr * DIM + cc;
        #pragma unroll
        for (int kk = 0; kk < 4; ++kk) {
            *reinterpret_cast<float4*>(&Xs[rr * WLD + cc + kk * 4]) =
                *reinterpret_cast<const float4*>(gx + kk * 4);
            *reinterpret_cast<float4*>(&Ws[rr * WLD + cc + kk * 4]) =
                *reinterpret_cast<const float4*>(gw + kk * 4);
        }
    }
    __syncthreads();

    const int r  = tid & 63;   // row within tile
    const int fg = tid >> 6;   // feature group (16 features each)
    float acc[16];
    #pragma unroll
    for (int j = 0; j < 16; ++j) acc[j] = 0.f;
    for (int d = 0; d < DIM; ++d) {
        const float x = Xs[r * WLD + d];
        #pragma unroll
        for (int j = 0; j < 16; ++j)
            acc[j] = fmaf(x, Ws[(fg * 16 + j) * WLD + d], acc[j]);
    }
    #pragma unroll
    for (int j = 0; j < 16; ++j)
        Os[(fg * 16 + j) * WLD + r] = fmaxf(acc[j], 0.f);
    __syncthreads();

    {   // coalesced transposed write: kfT[head][f][r0..r0+63]
        const int f  = tid >> 2;
        const int cc = (tid & 3) * 16;
        float* gdst = kfT + ((size_t)head * DIM + f) * SEQ + r0 + cc;
        #pragma unroll
        for (int kk = 0; kk < 4; ++kk)
            *reinterpret_cast<float4*>(gdst + kk * 4) =
                *reinterpret_cast<float4*>(&Os[f * WLD + cc + kk * 4]);
    }
}

// ---------------------------------------------------------------------------
// K2: per (head, 128-row block): qf on the fly, then two passes over kf tiles:
//     pass 1 -> online row (max, sum);  pass 2 -> write softmax to out.
// 8x8 register microtile per thread, 16x16 thread grid (tc minor for coalescing).
// ---------------------------------------------------------------------------
__global__ __launch_bounds__(256) void attn_kernel(const float* __restrict__ q,
                                                   const float* __restrict__ W,
                                                   const float* __restrict__ kfT,
                                                   float* __restrict__ out)
{
    __shared__ float A[64 * LDT];    // qf^T [f][r], swizzled r   (35840 B)
    __shared__ float Bt[64 * LDT];   // kf tile [f][c], swizzled c; W stage at start

    const int tid  = threadIdx.x;
    const int head = blockIdx.x >> 4;          // 16 row-blocks per head
    const int r0   = (blockIdx.x & 15) * BM;

    // ---- stage W into Bt as [f][d] (stride WLD, 16B aligned) ----
    {
        const int f  = tid >> 2;
        const int cc = (tid & 3) * 16;
        const float* gw = W + f * DIM + cc;
        #pragma unroll
        for (int kk = 0; kk < 4; ++kk)
            *reinterpret_cast<float4*>(&Bt[f * WLD + cc + kk * 4]) =
                *reinterpret_cast<const float4*>(gw + kk * 4);
    }
    __syncthreads();

    // ---- compute qf^T into A (two 64-row halves; q read from global, L1-hot) ----
    {
        const int r  = tid & 63;
        const int fg = tid >> 6;
        #pragma unroll
        for (int half = 0; half < 2; ++half) {
            const float* qrow = q + ((size_t)head * SEQ + r0 + half * 64 + r) * DIM;
            float acc[16];
            #pragma unroll
            for (int j = 0; j < 16; ++j) acc[j] = 0.f;
            for (int d4 = 0; d4 < DIM; d4 += 4) {
                const float4 xv = *reinterpret_cast<const float4*>(qrow + d4);
                const float xs[4] = {xv.x, xv.y, xv.z, xv.w};
                #pragma unroll
                for (int u = 0; u < 4; ++u) {
                    #pragma unroll
                    for (int j = 0; j < 16; ++j)
                        acc[j] = fmaf(xs[u], Bt[(fg * 16 + j) * WLD + d4 + u], acc[j]);
                }
            }
            #pragma unroll
            for (int j = 0; j < 16; ++j)
                A[(fg * 16 + j) * LDT + swz(half * 64 + r)] = fmaxf(acc[j], 0.f);
        }
    }
    __syncthreads();   // A ready; Bt (W) free for reuse

    const int tc   = tid & 15;
    const int tr   = tid >> 4;
    const int aoff = swz(tr * 8);
    const int boff = swz(tc * 8);
    const float* kfh = kfT + (size_t)head * DIM * SEQ;

    float m_th[8], l_th[8];
    #pragma unroll
    for (int i = 0; i < 8; ++i) { m_th[i] = -INFINITY; l_th[i] = 0.f; }

    // =========================== PASS 1: row stats ===========================
    for (int t = 0; t < NT; ++t) {
        {   // stage kf tile [64 f][128 c] -> Bt (swizzled)
            const int f  = tid >> 2;
            const int c0 = (tid & 3) * 32;
            const float* src = kfh + (size_t)f * SEQ + t * BN + c0;
            float* dst = &Bt[f * LDT + swz(c0)];
            #pragma unroll
            for (int kk = 0; kk < 8; ++kk)
                *reinterpret_cast<float4*>(dst + kk * 4) =
                    *reinterpret_cast<const float4*>(src + kk * 4);
        }
        __syncthreads();

        float s[8][8];
        #pragma unroll
        for (int i = 0; i < 8; ++i)
            #pragma unroll
            for (int j = 0; j < 8; ++j) s[i][j] = 0.f;

        #pragma unroll 2
        for (int k2 = 0; k2 < DIM; ++k2) {
            const float4 a0 = *reinterpret_cast<const float4*>(&A[k2 * LDT + aoff]);
            const float4 a1 = *reinterpret_cast<const float4*>(&A[k2 * LDT + aoff + 4]);
            const float4 b0 = *reinterpret_cast<const float4*>(&Bt[k2 * LDT + boff]);
            const float4 b1 = *reinterpret_cast<const float4*>(&Bt[k2 * LDT + boff + 4]);
            const float av[8] = {a0.x, a0.y, a0.z, a0.w, a1.x, a1.y, a1.z, a1.w};
            const float bv[8] = {b0.x, b0.y, b0.z, b0.w, b1.x, b1.y, b1.z, b1.w};
            #pragma unroll
            for (int i = 0; i < 8; ++i)
                #pragma unroll
                for (int j = 0; j < 8; ++j)
                    s[i][j] = fmaf(av[i], bv[j], s[i][j]);
        }

        // online softmax update (per thread: 8 rows x its 8 cols)
        #pragma unroll
        for (int i = 0; i < 8; ++i) {
            float tm = s[i][0];
            #pragma unroll
            for (int j = 1; j < 8; ++j) tm = fmaxf(tm, s[i][j]);
            const float mn = fmaxf(m_th[i], tm);
            float sum = 0.f;
            #pragma unroll
            for (int j = 0; j < 8; ++j) sum += __expf(s[i][j] - mn);
            l_th[i] = l_th[i] * __expf(m_th[i] - mn) + sum;
            m_th[i] = mn;
        }
        __syncthreads();   // before next tile overwrites Bt
    }

    // intra-wave reduce across the 16 lanes sharing each row (tc dimension)
    #pragma unroll
    for (int msk = 1; msk < 16; msk <<= 1) {
        #pragma unroll
        for (int i = 0; i < 8; ++i) {
            const float m2 = __shfl_xor(m_th[i], msk);
            const float l2 = __shfl_xor(l_th[i], msk);
            const float mn = fmaxf(m_th[i], m2);
            l_th[i] = l_th[i] * __expf(m_th[i] - mn) + l2 * __expf(m2 - mn);
            m_th[i] = mn;
        }
    }
    // every lane now holds the full-row stats for its 8 rows
    float mi[8], ri[8];
    #pragma unroll
    for (int i = 0; i < 8; ++i) { mi[i] = m_th[i]; ri[i] = 1.f / l_th[i]; }

    // =========================== PASS 2: write softmax =======================
    float* outp = out + ((size_t)head * SEQ + r0) * SEQ;
    for (int t = 0; t < NT; ++t) {
        {
            const int f  = tid >> 2;
            const int c0 = (tid & 3) * 32;
            const float* src = kfh + (size_t)f * SEQ + t * BN + c0;
            float* dst = &Bt[f * LDT + swz(c0)];
            #pragma unroll
            for (int kk = 0; kk < 8; ++kk)
                *reinterpret_cast<float4*>(dst + kk * 4) =
                    *reinterpret_cast<const float4*>(src + kk * 4);
        }
        __syncthreads();

        float s[8][8];
        #pragma unroll
        for (int i = 0; i < 8; ++i)
            #pragma unroll
            for (int j = 0; j < 8; ++j) s[i][j] = 0.f;

        #pragma unroll 2
        for (int k2 = 0; k2 < DIM; ++k2) {
            const float4 a0 = *reinterpret_cast<const float4*>(&A[k2 * LDT + aoff]);
            const float4 a1 = *reinterpret_cast<const float4*>(&A[k2 * LDT + aoff + 4]);
            const float4 b0 = *reinterpret_cast<const float4*>(&Bt[k2 * LDT + boff]);
            const float4 b1 = *reinterpret_cast<const float4*>(&Bt[k2 * LDT + boff + 4]);
            const float av[8] = {a0.x, a0.y, a0.z, a0.w, a1.x, a1.y, a1.z, a1.w};
            const float bv[8] = {b0.x, b0.y, b0.z, b0.w, b1.x, b1.y, b1.z, b1.w};
            #pragma unroll
            for (int i = 0; i < 8; ++i)
                #pragma unroll
                for (int j = 0; j < 8; ++j)
                    s[i][j] = fmaf(av[i], bv[j], s[i][j]);
        }

        #pragma unroll
        for (int i = 0; i < 8; ++i) {
            float4 o0, o1;
            o0.x = __expf(s[i][0] - mi[i]) * ri[i];
            o0.y = __expf(s[i][1] - mi[i]) * ri[i];
            o0.z = __expf(s[i][2] - mi[i]) * ri[i];
            o0.w = __expf(s[i][3] - mi[i]) * ri[i];
            o1.x = __expf(s[i][4] - mi[i]) * ri[i];
            o1.y = __expf(s[i][5] - mi[i]) * ri[i];
            o1.z = __expf(s[i][6] - mi[i]) * ri[i];
            o1.w = __expf(s[i][7] - mi[i]) * ri[i];
            const size_t off = (size_t)(tr * 8 + i) * SEQ + t * BN + tc * 8;
            *reinterpret_cast<float4*>(outp + off)     = o0;
            *reinterpret_cast<float4*>(outp + off + 4) = o1;
        }
        __syncthreads();
    }
}

// ---------------------------------------------------------------------------
// Launch. kfT (16 MiB) goes to d_ws when available; else it is staged in the
// attn_output region of d_out (read by attn_kernel, then overwritten by the
// v copy — stream-ordered, hazard-free). attn_output == v because the
// reference's softmax rows sum to 1.
// ---------------------------------------------------------------------------
extern "C" void kernel_launch(void* const* d_in, const int* in_sizes, int n_in,
                              void* d_out, int out_size, void* d_ws, size_t ws_size,
                              hipStream_t stream)
{
    const float* q = (const float*)d_in[0];
    const float* k = (const float*)d_in[1];
    const float* v = (const float*)d_in[2];
    const float* W = (const float*)d_in[3];
    float* out = (float*)d_out;

    const size_t kft_elems = (size_t)NHEAD * DIM * SEQ;   // 4 M floats = 16 MiB
    float* kfT = (d_ws != nullptr && ws_size >= kft_elems * sizeof(float))
                     ? (float*)d_ws
                     : out;                                // fallback: stage in out0
    float* attn = out + kft_elems;                         // attn_weights region

    kf_kernel<<<NHEAD * (SEQ / 64), 256, 0, stream>>>(k, W, kfT);
    attn_kernel<<<NHEAD * (SEQ / BM), 256, 0, stream>>>(q, W, kfT, attn);

    // output 0: attn_output == v (copy after attn_kernel consumed kfT)
    hipMemcpyAsync((void*)out, (const void*)v,
                   (size_t)NHEAD * SEQ * DIM * sizeof(float),
                   hipMemcpyDeviceToDevice, stream);
}

// Round 5
// 675.161 us; speedup vs baseline: 1.3342x; 1.3342x over previous
//
#include <hip/hip_runtime.h>
#include <cstddef>
#include <cstdint>

#define SEQ   2048
#define DIM   64
#define NHEAD 32
#define BM    128
#define BN    128
#define NT    (SEQ / BN)
#define WLD   68            // padded stride (floats) for [.][64] f32 LDS tiles

typedef __attribute__((ext_vector_type(8))) short short8v;  // 8 bf16 = one MFMA A/B frag

// f32 -> bf16 round-to-nearest-even
__device__ __forceinline__ unsigned short f2bf(float x) {
    union { float f; unsigned u; } v; v.f = x;
    unsigned r = v.u + 0x7FFFu + ((v.u >> 16) & 1u);
    return (unsigned short)(r >> 16);
}
__device__ __forceinline__ float bf2f(unsigned short h) {
    union { unsigned u; float f; } v; v.u = ((unsigned)h) << 16;
    return v.f;
}

// ---------------------------------------------------------------------------
// K1: kf = relu(k @ W^T) in f32, then split kf = kh + kl (bf16 pair), stored
// natural layout [head][s][f]. Wave w computes features w*16..w*16+15 for
// rows lane and lane+64 (W rows read once per block, LDS-broadcast).
// ---------------------------------------------------------------------------
__global__ __launch_bounds__(256) void kfsplit_kernel(const float* __restrict__ kin,
                                                      const float* __restrict__ W,
                                                      unsigned short* __restrict__ khg,
                                                      unsigned short* __restrict__ klg)
{
    __shared__ __align__(16) float Ws[64 * WLD];
    const int tid  = threadIdx.x;
    const int head = blockIdx.x >> 4;
    const int r0   = (blockIdx.x & 15) * BM;

    {   // stage W [64][WLD]
        const int f = tid >> 2, cc = (tid & 3) * 16;
        const float* gw = W + f * DIM + cc;
        #pragma unroll
        for (int kk = 0; kk < 4; ++kk)
            *reinterpret_cast<float4*>(&Ws[f * WLD + cc + kk * 4]) =
                *reinterpret_cast<const float4*>(gw + kk * 4);
    }
    __syncthreads();

    const int lane = tid & 63;
    const int wid  = tid >> 6;
    const float* kb = kin + ((size_t)head * SEQ + r0) * DIM;

    float acc0[16], acc1[16];
    #pragma unroll
    for (int j = 0; j < 16; ++j) { acc0[j] = 0.f; acc1[j] = 0.f; }

    for (int d4 = 0; d4 < 16; ++d4) {
        const float4 x0 = *reinterpret_cast<const float4*>(kb + (size_t)lane * DIM + d4 * 4);
        const float4 x1 = *reinterpret_cast<const float4*>(kb + (size_t)(64 + lane) * DIM + d4 * 4);
        #pragma unroll
        for (int j = 0; j < 16; ++j) {
            const float4 w4 = *reinterpret_cast<const float4*>(&Ws[(wid * 16 + j) * WLD + d4 * 4]);
            acc0[j] = fmaf(x0.x, w4.x, fmaf(x0.y, w4.y, fmaf(x0.z, w4.z, fmaf(x0.w, w4.w, acc0[j]))));
            acc1[j] = fmaf(x1.x, w4.x, fmaf(x1.y, w4.y, fmaf(x1.z, w4.z, fmaf(x1.w, w4.w, acc1[j]))));
        }
    }

#define SPLIT_ROW(ACC, ROWOFF)                                                          \
    do {                                                                                \
        unsigned hp[8], lp[8];                                                          \
        _Pragma("unroll")                                                               \
        for (int j2 = 0; j2 < 8; ++j2) {                                                \
            const float kf0 = fmaxf(ACC[2 * j2], 0.f);                                  \
            const float kf1 = fmaxf(ACC[2 * j2 + 1], 0.f);                              \
            const unsigned short h0 = f2bf(kf0), h1 = f2bf(kf1);                        \
            const unsigned short l0 = f2bf(kf0 - bf2f(h0));                             \
            const unsigned short l1 = f2bf(kf1 - bf2f(h1));                             \
            hp[j2] = (unsigned)h0 | ((unsigned)h1 << 16);                               \
            lp[j2] = (unsigned)l0 | ((unsigned)l1 << 16);                               \
        }                                                                               \
        unsigned short* dh = khg + ((size_t)head * SEQ + r0 + (ROWOFF)) * DIM + wid * 16; \
        unsigned short* dl = klg + ((size_t)head * SEQ + r0 + (ROWOFF)) * DIM + wid * 16; \
        uint4 a, b;                                                                     \
        a.x = hp[0]; a.y = hp[1]; a.z = hp[2]; a.w = hp[3];                             \
        b.x = hp[4]; b.y = hp[5]; b.z = hp[6]; b.w = hp[7];                             \
        *reinterpret_cast<uint4*>(dh) = a; *reinterpret_cast<uint4*>(dh + 8) = b;       \
        a.x = lp[0]; a.y = lp[1]; a.z = lp[2]; a.w = lp[3];                             \
        b.x = lp[4]; b.y = lp[5]; b.z = lp[6]; b.w = lp[7];                             \
        *reinterpret_cast<uint4*>(dl) = a; *reinterpret_cast<uint4*>(dl + 8) = b;       \
    } while (0)

    SPLIT_ROW(acc0, lane);
    SPLIT_ROW(acc1, 64 + lane);
#undef SPLIT_ROW
}

// ---------------------------------------------------------------------------
// K2: per (head, 128-row block):
//   phase 0: qf = relu(q W^T) f32 in LDS; build persistent A-frags qh/ql (regs)
//   pass 1 : MFMA scores per 128-col tile (3-term split-bf16), online (m,l)
//   cross-wave (m,l) combine via LDS  (waves see half-rows)
//   pass 2 : recompute scores, write normalized softmax (f32) to out
// 4 waves in 2x2 grid; wave owns 64x64 of the 128x128 tile.
// ---------------------------------------------------------------------------
__global__ __launch_bounds__(256, 2) void attn_kernel(const float* __restrict__ q,
                                                      const float* __restrict__ W,
                                                      const unsigned short* __restrict__ khg,
                                                      const unsigned short* __restrict__ klg,
                                                      float* __restrict__ out)
{
    __shared__ __align__(16) float lds[13056];     // 52224 B
    float* Ws = lds;                                // [64][WLD]  (phase 0)
    float* qf = lds + 4352;                         // [128][WLD] (phase 0)
    unsigned short* khs = reinterpret_cast<unsigned short*>(lds);         // 16 KiB (passes)
    unsigned short* kls = reinterpret_cast<unsigned short*>(lds + 4096);  // 16 KiB (passes)
    float* mbuf = lds + 8192;                       // [4][64] row-max   (byte 32768)
    float* lbuf = lds + 8448;                       // [4][64] row-sum

    const int tid  = threadIdx.x;
    const int head = blockIdx.x >> 4;
    const int r0   = (blockIdx.x & 15) * BM;
    const int lane = tid & 63;
    const int wid  = tid >> 6;

    // ---- phase 0a: stage W ----
    {
        const int f = tid >> 2, cc = (tid & 3) * 16;
        const float* gw = W + f * DIM + cc;
        #pragma unroll
        for (int kk = 0; kk < 4; ++kk)
            *reinterpret_cast<float4*>(&Ws[f * WLD + cc + kk * 4]) =
                *reinterpret_cast<const float4*>(gw + kk * 4);
    }
    __syncthreads();

    // ---- phase 0b: qf (wave wid -> features wid*16..+15; lanes -> rows lane, lane+64)
    {
        const float* qb = q + ((size_t)head * SEQ + r0) * DIM;
        float a0[16], a1[16];
        #pragma unroll
        for (int j = 0; j < 16; ++j) { a0[j] = 0.f; a1[j] = 0.f; }
        for (int d4 = 0; d4 < 16; ++d4) {
            const float4 x0 = *reinterpret_cast<const float4*>(qb + (size_t)lane * DIM + d4 * 4);
            const float4 x1 = *reinterpret_cast<const float4*>(qb + (size_t)(64 + lane) * DIM + d4 * 4);
            #pragma unroll
            for (int j = 0; j < 16; ++j) {
                const float4 w4 = *reinterpret_cast<const float4*>(&Ws[(wid * 16 + j) * WLD + d4 * 4]);
                a0[j] = fmaf(x0.x, w4.x, fmaf(x0.y, w4.y, fmaf(x0.z, w4.z, fmaf(x0.w, w4.w, a0[j]))));
                a1[j] = fmaf(x1.x, w4.x, fmaf(x1.y, w4.y, fmaf(x1.z, w4.z, fmaf(x1.w, w4.w, a1[j]))));
            }
        }
        #pragma unroll
        for (int j = 0; j < 16; ++j) {
            qf[(size_t)lane * WLD + wid * 16 + j]        = fmaxf(a0[j], 0.f);
            qf[(size_t)(64 + lane) * WLD + wid * 16 + j] = fmaxf(a1[j], 0.f);
        }
    }
    __syncthreads();

    // ---- phase 0c: persistent A-frags (rows: wrow+rf*16+lr, k: ks*32+lh*8) ----
    const int lr = lane & 15, lh = lane >> 4;
    const int wrow = (wid >> 1) * 64, wcol = (wid & 1) * 64;
    short8v qh[4][2], ql[4][2];
    #pragma unroll
    for (int rf = 0; rf < 4; ++rf)
        #pragma unroll
        for (int ks = 0; ks < 2; ++ks) {
            const float* src = &qf[(size_t)(wrow + rf * 16 + lr) * WLD + ks * 32 + lh * 8];
            short8v h, l;
            #pragma unroll
            for (int e = 0; e < 8; ++e) {
                const float x = src[e];
                const unsigned short hh = f2bf(x);
                h[e] = (short)hh;
                l[e] = (short)f2bf(x - bf2f(hh));
            }
            qh[rf][ks] = h;
            ql[rf][ks] = l;
        }
    __syncthreads();   // qf dead; LDS reused for kh/kl tiles

    const size_t khead = (size_t)head * SEQ * DIM;
    const int sc = tid >> 1, sf = tid & 1;          // staging: row sc, 32-feat half sf
    const int wbase = sc * 128 + sf * 64;           // byte offset within kh tile
    const int wsw = (sc & 7) << 4;                  // XOR swizzle

#define STAGE(T)                                                                          \
    do {                                                                                  \
        const unsigned short* srch = khg + khead + (size_t)((T) * BN + sc) * DIM + sf * 32; \
        const unsigned short* srcl = klg + khead + (size_t)((T) * BN + sc) * DIM + sf * 32; \
        _Pragma("unroll")                                                                 \
        for (int j = 0; j < 4; ++j) {                                                     \
            const uint4 vh = *reinterpret_cast<const uint4*>(srch + j * 8);               \
            const uint4 vl = *reinterpret_cast<const uint4*>(srcl + j * 8);               \
            *reinterpret_cast<uint4*>(reinterpret_cast<char*>(khs) + ((wbase + j * 16) ^ wsw)) = vh; \
            *reinterpret_cast<uint4*>(reinterpret_cast<char*>(kls) + ((wbase + j * 16) ^ wsw)) = vl; \
        }                                                                                 \
    } while (0)

#define COMPUTE_ACC()                                                                     \
    do {                                                                                  \
        _Pragma("unroll")                                                                 \
        for (int cf = 0; cf < 4; ++cf) {                                                  \
            const int c  = wcol + cf * 16 + lr;                                           \
            const int rb = c * 128 + lh * 16;                                             \
            const int sw = (c & 7) << 4;                                                  \
            const short8v bh0 = *reinterpret_cast<const short8v*>(reinterpret_cast<const char*>(khs) + ((rb) ^ sw));        \
            const short8v bh1 = *reinterpret_cast<const short8v*>(reinterpret_cast<const char*>(khs) + ((rb + 64) ^ sw));   \
            const short8v bl0 = *reinterpret_cast<const short8v*>(reinterpret_cast<const char*>(kls) + ((rb) ^ sw));        \
            const short8v bl1 = *reinterpret_cast<const short8v*>(reinterpret_cast<const char*>(kls) + ((rb + 64) ^ sw));   \
            _Pragma("unroll")                                                             \
            for (int rf = 0; rf < 4; ++rf) {                                              \
                float4 a = acc[rf][cf];                                                   \
                a = __builtin_amdgcn_mfma_f32_16x16x32_bf16(qh[rf][0], bh0, a, 0, 0, 0);  \
                a = __builtin_amdgcn_mfma_f32_16x16x32_bf16(ql[rf][0], bh0, a, 0, 0, 0);  \
                a = __builtin_amdgcn_mfma_f32_16x16x32_bf16(qh[rf][0], bl0, a, 0, 0, 0);  \
                a = __builtin_amdgcn_mfma_f32_16x16x32_bf16(qh[rf][1], bh1, a, 0, 0, 0);  \
                a = __builtin_amdgcn_mfma_f32_16x16x32_bf16(ql[rf][1], bh1, a, 0, 0, 0);  \
                a = __builtin_amdgcn_mfma_f32_16x16x32_bf16(qh[rf][1], bl1, a, 0, 0, 0);  \
                acc[rf][cf] = a;                                                          \
            }                                                                             \
        }                                                                                 \
    } while (0)

    typedef __attribute__((ext_vector_type(4))) float float4; // shadow HIP float4 for acc
    float mrow[16], lrow[16];
    #pragma unroll
    for (int i = 0; i < 16; ++i) { mrow[i] = -INFINITY; lrow[i] = 0.f; }

    // ============================ PASS 1: row stats ============================
    for (int t = 0; t < NT; ++t) {
        STAGE(t);
        __syncthreads();
        float4 acc[4][4] = {};
        COMPUTE_ACC();
        #pragma unroll
        for (int rf = 0; rf < 4; ++rf)
            #pragma unroll
            for (int q4 = 0; q4 < 4; ++q4) {
                const int i = rf * 4 + q4;
                const float v0 = acc[rf][0][q4], v1 = acc[rf][1][q4];
                const float v2 = acc[rf][2][q4], v3 = acc[rf][3][q4];
                const float tm = fmaxf(fmaxf(v0, v1), fmaxf(v2, v3));
                const float mn = fmaxf(mrow[i], tm);
                const float p = __expf(v0 - mn) + __expf(v1 - mn) +
                                __expf(v2 - mn) + __expf(v3 - mn);
                lrow[i] = lrow[i] * __expf(mrow[i] - mn) + p;
                mrow[i] = mn;
            }
        __syncthreads();
    }

    // intra-wave reduce over the 16 col-owning lanes (masks 1,2,4,8)
    #pragma unroll
    for (int s = 0; s < 4; ++s) {
        const int msk = 1 << s;
        #pragma unroll
        for (int i = 0; i < 16; ++i) {
            const float m2 = __shfl_xor(mrow[i], msk);
            const float l2 = __shfl_xor(lrow[i], msk);
            const float mn = fmaxf(mrow[i], m2);
            lrow[i] = lrow[i] * __expf(mrow[i] - mn) + l2 * __expf(m2 - mn);
            mrow[i] = mn;
        }
    }

    // ---- cross-wave combine: waves wid and wid^1 each saw half the columns ----
    if (lr == 0) {
        #pragma unroll
        for (int i = 0; i < 16; ++i) {
            const int row16 = (i >> 2) * 16 + lh * 4 + (i & 3);   // 0..63
            mbuf[wid * 64 + row16] = mrow[i];
            lbuf[wid * 64 + row16] = lrow[i];
        }
    }
    __syncthreads();
    {
        const int pw = wid ^ 1;   // partner wave: same rows, other column half
        #pragma unroll
        for (int i = 0; i < 16; ++i) {
            const int row16 = (i >> 2) * 16 + lh * 4 + (i & 3);
            const float m2 = mbuf[pw * 64 + row16];
            const float l2 = lbuf[pw * 64 + row16];
            const float mn = fmaxf(mrow[i], m2);
            lrow[i] = lrow[i] * __expf(mrow[i] - mn) + l2 * __expf(m2 - mn);
            mrow[i] = mn;
        }
    }
    #pragma unroll
    for (int i = 0; i < 16; ++i) lrow[i] = 1.0f / lrow[i];

    // ============================ PASS 2: write softmax ========================
    float* outp = out + ((size_t)head * SEQ + r0) * SEQ;
    for (int t = 0; t < NT; ++t) {
        STAGE(t);
        __syncthreads();
        float4 acc[4][4] = {};
        COMPUTE_ACC();
        const int col0 = t * BN + wcol;
        #pragma unroll
        for (int rf = 0; rf < 4; ++rf)
            #pragma unroll
            for (int q4 = 0; q4 < 4; ++q4) {
                const int i = rf * 4 + q4;
                const int row = wrow + rf * 16 + lh * 4 + q4;
                float* rp = outp + (size_t)row * SEQ + col0 + lr;
                rp[0]  = __expf(acc[rf][0][q4] - mrow[i]) * lrow[i];
                rp[16] = __expf(acc[rf][1][q4] - mrow[i]) * lrow[i];
                rp[32] = __expf(acc[rf][2][q4] - mrow[i]) * lrow[i];
                rp[48] = __expf(acc[rf][3][q4] - mrow[i]) * lrow[i];
            }
        __syncthreads();
    }
#undef STAGE
#undef COMPUTE_ACC
}

// ---------------------------------------------------------------------------
// kh/kl (16 MiB total) go to d_ws when big enough; else they exactly fill
// the attn_output region of d_out (read by attn_kernel, then overwritten by
// the v copy — stream-ordered). attn_output == v (softmax rows sum to 1).
// ---------------------------------------------------------------------------
extern "C" void kernel_launch(void* const* d_in, const int* in_sizes, int n_in,
                              void* d_out, int out_size, void* d_ws, size_t ws_size,
                              hipStream_t stream)
{
    const float* q = (const float*)d_in[0];
    const float* k = (const float*)d_in[1];
    const float* v = (const float*)d_in[2];
    const float* W = (const float*)d_in[3];
    float* out = (float*)d_out;

    const size_t nkf = (size_t)NHEAD * SEQ * DIM;   // 4,194,304 elements
    unsigned short* kh;
    if (d_ws != nullptr && ws_size >= nkf * 4u) {   // 16 MiB for kh+kl
        kh = (unsigned short*)d_ws;
    } else {
        kh = (unsigned short*)out;                  // exactly fills out0 region
    }
    unsigned short* kl = kh + nkf;
    float* attn = out + nkf;

    kfsplit_kernel<<<NHEAD * (SEQ / BM), 256, 0, stream>>>(k, W, kh, kl);
    attn_kernel<<<NHEAD * (SEQ / BM), 256, 0, stream>>>(q, W, kh, kl, attn);

    hipMemcpyAsync((void*)out, (const void*)v, nkf * sizeof(float),
                   hipMemcpyDeviceToDevice, stream);
}

// Round 6
// 653.345 us; speedup vs baseline: 1.3787x; 1.0334x over previous
//
#include <hip/hip_runtime.h>
#include <cstddef>
#include <cstdint>

#define SEQ   2048
#define DIM   64
#define NHEAD 32
#define BM    128
#define BN    128
#define NT    (SEQ / BN)
#define WLD   68            // padded stride (floats) for [.][64] f32 LDS tiles

typedef __attribute__((ext_vector_type(8))) short short8v;  // 8 bf16 = one MFMA A/B frag
typedef __attribute__((ext_vector_type(4))) float f32x4;    // MFMA accumulator

// f32 -> bf16 round-to-nearest-even
__device__ __forceinline__ unsigned short f2bf(float x) {
    union { float f; unsigned u; } v; v.f = x;
    unsigned r = v.u + 0x7FFFu + ((v.u >> 16) & 1u);
    return (unsigned short)(r >> 16);
}
__device__ __forceinline__ float bf2f(unsigned short h) {
    union { unsigned u; float f; } v; v.u = ((unsigned)h) << 16;
    return v.f;
}

// async global->LDS, 16B/lane; LDS dest = wave-uniform base + lane*16
__device__ __forceinline__ void gl_lds16(const void* g, void* l) {
    __builtin_amdgcn_global_load_lds(
        (const __attribute__((address_space(1))) unsigned int*)g,
        (__attribute__((address_space(3))) unsigned int*)l,
        16, 0, 0);
}

// ---------------------------------------------------------------------------
// K1: kf = relu(k @ W^T) f32, split kf = kh + kl (bf16 pair), layout [head][s][f].
// ---------------------------------------------------------------------------
__global__ __launch_bounds__(256) void kfsplit_kernel(const float* __restrict__ kin,
                                                      const float* __restrict__ W,
                                                      unsigned short* __restrict__ khg,
                                                      unsigned short* __restrict__ klg)
{
    __shared__ __align__(16) float Ws[64 * WLD];
    const int tid  = threadIdx.x;
    const int head = blockIdx.x >> 4;
    const int r0   = (blockIdx.x & 15) * BM;

    {   // stage W [64][WLD]
        const int f = tid >> 2, cc = (tid & 3) * 16;
        const float* gw = W + f * DIM + cc;
        #pragma unroll
        for (int kk = 0; kk < 4; ++kk)
            *reinterpret_cast<float4*>(&Ws[f * WLD + cc + kk * 4]) =
                *reinterpret_cast<const float4*>(gw + kk * 4);
    }
    __syncthreads();

    const int lane = tid & 63;
    const int wid  = tid >> 6;
    const float* kb = kin + ((size_t)head * SEQ + r0) * DIM;

    float acc0[16], acc1[16];
    #pragma unroll
    for (int j = 0; j < 16; ++j) { acc0[j] = 0.f; acc1[j] = 0.f; }

    for (int d4 = 0; d4 < 16; ++d4) {
        const float4 x0 = *reinterpret_cast<const float4*>(kb + (size_t)lane * DIM + d4 * 4);
        const float4 x1 = *reinterpret_cast<const float4*>(kb + (size_t)(64 + lane) * DIM + d4 * 4);
        #pragma unroll
        for (int j = 0; j < 16; ++j) {
            const float4 w4 = *reinterpret_cast<const float4*>(&Ws[(wid * 16 + j) * WLD + d4 * 4]);
            acc0[j] = fmaf(x0.x, w4.x, fmaf(x0.y, w4.y, fmaf(x0.z, w4.z, fmaf(x0.w, w4.w, acc0[j]))));
            acc1[j] = fmaf(x1.x, w4.x, fmaf(x1.y, w4.y, fmaf(x1.z, w4.z, fmaf(x1.w, w4.w, acc1[j]))));
        }
    }

#define SPLIT_ROW(ACC, ROWOFF)                                                          \
    do {                                                                                \
        unsigned hp[8], lp[8];                                                          \
        _Pragma("unroll")                                                               \
        for (int j2 = 0; j2 < 8; ++j2) {                                                \
            const float kf0 = fmaxf(ACC[2 * j2], 0.f);                                  \
            const float kf1 = fmaxf(ACC[2 * j2 + 1], 0.f);                              \
            const unsigned short h0 = f2bf(kf0), h1 = f2bf(kf1);                        \
            const unsigned short l0 = f2bf(kf0 - bf2f(h0));                             \
            const unsigned short l1 = f2bf(kf1 - bf2f(h1));                             \
            hp[j2] = (unsigned)h0 | ((unsigned)h1 << 16);                               \
            lp[j2] = (unsigned)l0 | ((unsigned)l1 << 16);                               \
        }                                                                               \
        unsigned short* dh = khg + ((size_t)head * SEQ + r0 + (ROWOFF)) * DIM + wid * 16; \
        unsigned short* dl = klg + ((size_t)head * SEQ + r0 + (ROWOFF)) * DIM + wid * 16; \
        uint4 a, b;                                                                     \
        a.x = hp[0]; a.y = hp[1]; a.z = hp[2]; a.w = hp[3];                             \
        b.x = hp[4]; b.y = hp[5]; b.z = hp[6]; b.w = hp[7];                             \
        *reinterpret_cast<uint4*>(dh) = a; *reinterpret_cast<uint4*>(dh + 8) = b;       \
        a.x = lp[0]; a.y = lp[1]; a.z = lp[2]; a.w = lp[3];                             \
        b.x = lp[4]; b.y = lp[5]; b.z = lp[6]; b.w = lp[7];                             \
        *reinterpret_cast<uint4*>(dl) = a; *reinterpret_cast<uint4*>(dl + 8) = b;       \
    } while (0)

    SPLIT_ROW(acc0, lane);
    SPLIT_ROW(acc1, 64 + lane);
#undef SPLIT_ROW
}

// ---------------------------------------------------------------------------
// K2 v2: double-buffered async staging via global_load_lds (pre-swizzled global
// source, linear LDS dest, swizzled reads). One barrier per tile.
// LDS map (bytes):
//   buf0: kh 0..16383, kl 16384..32767
//   buf1: kh 32768..49151, kl 49152..65535
//   phase 0: Ws at 0..17407, qf at 32768..67583 (dead after 0c)
//   stats: mbuf 65536..66559, lbuf 66560..67583 (live only between passes)
// ---------------------------------------------------------------------------
__global__ __launch_bounds__(256, 2) void attn_kernel(const float* __restrict__ q,
                                                      const float* __restrict__ W,
                                                      const unsigned short* __restrict__ khg,
                                                      const unsigned short* __restrict__ klg,
                                                      float* __restrict__ out)
{
    __shared__ __align__(16) unsigned char lds_raw[67584];
    float* Ws   = (float*)lds_raw;                  // [64][WLD] phase 0
    float* qf   = (float*)(lds_raw + 32768);        // [128][WLD] phase 0
    float* mbuf = (float*)(lds_raw + 65536);        // [4][64]
    float* lbuf = (float*)(lds_raw + 66560);        // [4][64]

    const int tid  = threadIdx.x;
    const int head = blockIdx.x >> 4;
    const int r0   = (blockIdx.x & 15) * BM;
    const int lane = tid & 63;
    const int wid  = tid >> 6;

    const size_t khead_b = (size_t)head * SEQ * DIM * 2;   // byte offset of head
    const unsigned char* gkh = (const unsigned char*)khg + khead_b;
    const unsigned char* gkl = (const unsigned char*)klg + khead_b;

    // stage one 16KB kh tile + 16KB kl tile into buf (linear LDS, pre-swizzled src)
#define STAGE(BUF, T)                                                                   \
    do {                                                                                \
        const unsigned char* skh = gkh + (size_t)(T) * (BN * DIM * 2);                  \
        const unsigned char* skl = gkl + (size_t)(T) * (BN * DIM * 2);                  \
        unsigned char* lkh = lds_raw + (BUF) * 32768;                                   \
        unsigned char* lkl = lkh + 16384;                                               \
        _Pragma("unroll")                                                               \
        for (int i_ = 0; i_ < 4; ++i_) {                                                \
            const unsigned o_   = wid * 4096 + i_ * 1024 + lane * 16;                   \
            const unsigned row_ = o_ >> 7;                                              \
            const unsigned u_   = (o_ & ~127u) | ((o_ & 127u) ^ ((row_ & 7u) << 4));    \
            gl_lds16(skh + u_, lkh + wid * 4096 + i_ * 1024);                           \
            gl_lds16(skl + u_, lkl + wid * 4096 + i_ * 1024);                           \
        }                                                                               \
    } while (0)

    // ---- phase 0a: stage W into Ws ----
    {
        const int f = tid >> 2, cc = (tid & 3) * 16;
        const float* gw = W + f * DIM + cc;
        #pragma unroll
        for (int kk = 0; kk < 4; ++kk)
            *reinterpret_cast<float4*>(&Ws[f * WLD + cc + kk * 4]) =
                *reinterpret_cast<const float4*>(gw + kk * 4);
    }
    __syncthreads();

    // ---- phase 0b: qf = relu(q W^T) into LDS ----
    {
        const float* qb = q + ((size_t)head * SEQ + r0) * DIM;
        float a0[16], a1[16];
        #pragma unroll
        for (int j = 0; j < 16; ++j) { a0[j] = 0.f; a1[j] = 0.f; }
        for (int d4 = 0; d4 < 16; ++d4) {
            const float4 x0 = *reinterpret_cast<const float4*>(qb + (size_t)lane * DIM + d4 * 4);
            const float4 x1 = *reinterpret_cast<const float4*>(qb + (size_t)(64 + lane) * DIM + d4 * 4);
            #pragma unroll
            for (int j = 0; j < 16; ++j) {
                const float4 w4 = *reinterpret_cast<const float4*>(&Ws[(wid * 16 + j) * WLD + d4 * 4]);
                a0[j] = fmaf(x0.x, w4.x, fmaf(x0.y, w4.y, fmaf(x0.z, w4.z, fmaf(x0.w, w4.w, a0[j]))));
                a1[j] = fmaf(x1.x, w4.x, fmaf(x1.y, w4.y, fmaf(x1.z, w4.z, fmaf(x1.w, w4.w, a1[j]))));
            }
        }
        #pragma unroll
        for (int j = 0; j < 16; ++j) {
            qf[(size_t)lane * WLD + wid * 16 + j]        = fmaxf(a0[j], 0.f);
            qf[(size_t)(64 + lane) * WLD + wid * 16 + j] = fmaxf(a1[j], 0.f);
        }
    }
    __syncthreads();          // qf ready; Ws dead

    STAGE(0, 0);              // prefetch tile 0 into buf0 (bytes 0..32767, disjoint from qf)

    // ---- phase 0c: persistent A-frags (rows: wrow+rf*16+lr, k: ks*32+lh*8) ----
    const int lr = lane & 15, lh = lane >> 4;
    const int wrow = (wid >> 1) * 64, wcol = (wid & 1) * 64;
    short8v qh[4][2], ql[4][2];
    #pragma unroll
    for (int rf = 0; rf < 4; ++rf)
        #pragma unroll
        for (int ks = 0; ks < 2; ++ks) {
            const float* src = &qf[(size_t)(wrow + rf * 16 + lr) * WLD + ks * 32 + lh * 8];
            short8v h, l;
            #pragma unroll
            for (int e = 0; e < 8; ++e) {
                const float x = src[e];
                const unsigned short hh = f2bf(x);
                h[e] = (short)hh;
                l[e] = (short)f2bf(x - bf2f(hh));
            }
            qh[rf][ks] = h;
            ql[rf][ks] = l;
        }
    __syncthreads();          // qf dead; buf0 loads drained (vmcnt 0 at barrier)

#define COMPUTE_ACC(BUF)                                                                  \
    do {                                                                                  \
        const unsigned char* khb = lds_raw + (BUF) * 32768;                               \
        const unsigned char* klb = khb + 16384;                                           \
        _Pragma("unroll")                                                                 \
        for (int cf = 0; cf < 4; ++cf) {                                                  \
            const int c  = wcol + cf * 16 + lr;                                           \
            const int rb = c * 128 + lh * 16;                                             \
            const int sw = (c & 7) << 4;                                                  \
            const short8v bh0 = *reinterpret_cast<const short8v*>(khb + ((rb) ^ sw));     \
            const short8v bh1 = *reinterpret_cast<const short8v*>(khb + ((rb + 64) ^ sw));\
            const short8v bl0 = *reinterpret_cast<const short8v*>(klb + ((rb) ^ sw));     \
            const short8v bl1 = *reinterpret_cast<const short8v*>(klb + ((rb + 64) ^ sw));\
            _Pragma("unroll")                                                             \
            for (int rf = 0; rf < 4; ++rf) {                                              \
                f32x4 a = acc[rf][cf];                                                    \
                a = __builtin_amdgcn_mfma_f32_16x16x32_bf16(qh[rf][0], bh0, a, 0, 0, 0);  \
                a = __builtin_amdgcn_mfma_f32_16x16x32_bf16(ql[rf][0], bh0, a, 0, 0, 0);  \
                a = __builtin_amdgcn_mfma_f32_16x16x32_bf16(qh[rf][0], bl0, a, 0, 0, 0);  \
                a = __builtin_amdgcn_mfma_f32_16x16x32_bf16(qh[rf][1], bh1, a, 0, 0, 0);  \
                a = __builtin_amdgcn_mfma_f32_16x16x32_bf16(ql[rf][1], bh1, a, 0, 0, 0);  \
                a = __builtin_amdgcn_mfma_f32_16x16x32_bf16(qh[rf][1], bl1, a, 0, 0, 0);  \
                acc[rf][cf] = a;                                                          \
            }                                                                             \
        }                                                                                 \
    } while (0)

    float mrow[16], lrow[16];
    #pragma unroll
    for (int i = 0; i < 16; ++i) { mrow[i] = -INFINITY; lrow[i] = 0.f; }

    // ============================ PASS 1: row stats ============================
    {
        int cur = 0;
        for (int t = 0; t < NT; ++t) {
            if (t + 1 < NT) STAGE(cur ^ 1, t + 1);   // async loads fly under compute
            f32x4 acc[4][4] = {};
            COMPUTE_ACC(cur);
            #pragma unroll
            for (int rf = 0; rf < 4; ++rf)
                #pragma unroll
                for (int q4 = 0; q4 < 4; ++q4) {
                    const int i = rf * 4 + q4;
                    const float v0 = acc[rf][0][q4], v1 = acc[rf][1][q4];
                    const float v2 = acc[rf][2][q4], v3 = acc[rf][3][q4];
                    const float tm = fmaxf(fmaxf(v0, v1), fmaxf(v2, v3));
                    const float mn = fmaxf(mrow[i], tm);
                    const float p = __expf(v0 - mn) + __expf(v1 - mn) +
                                    __expf(v2 - mn) + __expf(v3 - mn);
                    lrow[i] = lrow[i] * __expf(mrow[i] - mn) + p;
                    mrow[i] = mn;
                }
            __syncthreads();   // done reading cur; next buffer's loads drained
            cur ^= 1;
        }
    }

    STAGE(0, 0);               // prefetch pass-2 tile 0 (overlaps the reduce)

    // intra-wave reduce over the 16 col-owning lanes (masks 1,2,4,8)
    #pragma unroll
    for (int s = 0; s < 4; ++s) {
        const int msk = 1 << s;
        #pragma unroll
        for (int i = 0; i < 16; ++i) {
            const float m2 = __shfl_xor(mrow[i], msk);
            const float l2 = __shfl_xor(lrow[i], msk);
            const float mn = fmaxf(mrow[i], m2);
            lrow[i] = lrow[i] * __expf(mrow[i] - mn) + l2 * __expf(m2 - mn);
            mrow[i] = mn;
        }
    }

    // cross-wave combine: waves wid and wid^1 each saw half the columns
    if (lr == 0) {
        #pragma unroll
        for (int i = 0; i < 16; ++i) {
            const int row16 = (i >> 2) * 16 + lh * 4 + (i & 3);   // 0..63
            mbuf[wid * 64 + row16] = mrow[i];
            lbuf[wid * 64 + row16] = lrow[i];
        }
    }
    __syncthreads();           // stats visible; pass-2 prefetch drained
    {
        const int pw = wid ^ 1;
        #pragma unroll
        for (int i = 0; i < 16; ++i) {
            const int row16 = (i >> 2) * 16 + lh * 4 + (i & 3);
            const float m2 = mbuf[pw * 64 + row16];
            const float l2 = lbuf[pw * 64 + row16];
            const float mn = fmaxf(mrow[i], m2);
            lrow[i] = lrow[i] * __expf(mrow[i] - mn) + l2 * __expf(m2 - mn);
            mrow[i] = mn;
        }
    }
    #pragma unroll
    for (int i = 0; i < 16; ++i) lrow[i] = 1.0f / lrow[i];

    // ============================ PASS 2: write softmax ========================
    float* outp = out + ((size_t)head * SEQ + r0) * SEQ;
    {
        int cur = 0;
        for (int t = 0; t < NT; ++t) {
            if (t + 1 < NT) STAGE(cur ^ 1, t + 1);
            f32x4 acc[4][4] = {};
            COMPUTE_ACC(cur);
            const int col0 = t * BN + wcol;
            #pragma unroll
            for (int rf = 0; rf < 4; ++rf)
                #pragma unroll
                for (int q4 = 0; q4 < 4; ++q4) {
                    const int i = rf * 4 + q4;
                    const int row = wrow + rf * 16 + lh * 4 + q4;
                    float* rp = outp + (size_t)row * SEQ + col0 + lr;
                    rp[0]  = __expf(acc[rf][0][q4] - mrow[i]) * lrow[i];
                    rp[16] = __expf(acc[rf][1][q4] - mrow[i]) * lrow[i];
                    rp[32] = __expf(acc[rf][2][q4] - mrow[i]) * lrow[i];
                    rp[48] = __expf(acc[rf][3][q4] - mrow[i]) * lrow[i];
                }
            __syncthreads();
            cur ^= 1;
        }
    }
#undef STAGE
#undef COMPUTE_ACC
}

// ---------------------------------------------------------------------------
// kh/kl (16 MiB total) go to d_ws when big enough; else they exactly fill the
// attn_output region of d_out (read by attn_kernel, then overwritten by the
// v copy — stream-ordered). attn_output == v (softmax rows sum to 1).
// ---------------------------------------------------------------------------
extern "C" void kernel_launch(void* const* d_in, const int* in_sizes, int n_in,
                              void* d_out, int out_size, void* d_ws, size_t ws_size,
                              hipStream_t stream)
{
    const float* q = (const float*)d_in[0];
    const float* k = (const float*)d_in[1];
    const float* v = (const float*)d_in[2];
    const float* W = (const float*)d_in[3];
    float* out = (float*)d_out;

    const size_t nkf = (size_t)NHEAD * SEQ * DIM;   // 4,194,304 elements
    unsigned short* kh;
    if (d_ws != nullptr && ws_size >= nkf * 4u) {
        kh = (unsigned short*)d_ws;
    } else {
        kh = (unsigned short*)out;
    }
    unsigned short* kl = kh + nkf;
    float* attn = out + nkf;

    kfsplit_kernel<<<NHEAD * (SEQ / BM), 256, 0, stream>>>(k, W, kh, kl);
    attn_kernel<<<NHEAD * (SEQ / BM), 256, 0, stream>>>(q, W, kh, kl, attn);

    hipMemcpyAsync((void*)out, (const void*)v, nkf * sizeof(float),
                   hipMemcpyDeviceToDevice, stream);
}